// Round 8
// baseline (186.511 us; speedup 1.0000x reference)
//
#include <hip/hip_runtime.h>

namespace {
constexpr int Sdim = 128;
constexpr int Tdim = 64;
constexpr int U2c  = 16;
constexpr int PT   = 32;                 // pixel locations per block (128B yt rows)
constexpr int NTHREADS = 512;
constexpr int PP = Sdim * Sdim;          // 16384 pixels
}

// No LDS, no barriers: weights stream through L1 (hot window ~4KB since waves are
// t-lockstep); yt streams from HBM with 512B/instr coalescing. (512,2): VGPR
// budget 128 (R2 lesson: never over-clamp).
__global__ __launch_bounds__(NTHREADS, 2)
void upscale_fused(const float* __restrict__ yt,
                   const float* __restrict__ wgt,
                   const float* __restrict__ bias,
                   float* __restrict__ out)
{
    const int tid   = threadIdx.x;
    const int p_blk = blockIdx.x * PT;

    // mapping: 2p x 4b x 8u per thread (64 FMA/t-step, acc = 64 VGPR)
    const int pg = tid & 15;            // p0, p0+1
    const int bq = (tid >> 4) & 15;     // b = bq + 16*k, k=0..3
    const int ug = tid >> 8;            // u half: u in [ug*8, ug*8+8)
    const int p0 = p_blk + pg * 2;

    // weight rows, float4-granular: row p has 256 float4; (t, u-quad q) at t*4+q.
    // Pre-offset by ug's first quad (q = 2*ug).
    const float4* wgt4 = reinterpret_cast<const float4*>(wgt);
    const float4* wr0  = wgt4 + (size_t)p0 * 256 + 2 * ug;
    const float4* wr1  = wr0 + 256;

    // ---- init acc with bias (same for all 4 b) -----------------------------------
    float acc[4][2][8];   // [k][jp][u_local]
    #pragma unroll
    for (int jp = 0; jp < 2; ++jp) {
        const float* bp = bias + (size_t)(p0 + jp) * U2c + ug * 8;
        const float4 q0 = *reinterpret_cast<const float4*>(bp);
        const float4 q1 = *reinterpret_cast<const float4*>(bp + 4);
        const float bb[8] = {q0.x,q0.y,q0.z,q0.w, q1.x,q1.y,q1.z,q1.w};
        #pragma unroll
        for (int k = 0; k < 4; ++k)
            #pragma unroll
            for (int j = 0; j < 8; ++j) acc[k][jp][j] = bb[j];
    }

    // ---- yt: float2 per (b,t); wave = 4 x 128B segments, 512B/instr, no dup ------
    const float* ybase = yt + (size_t)bq * ((size_t)Tdim * PP) + p0;
    auto ldy = [&](int t, float2* dst) {
        #pragma unroll
        for (int k = 0; k < 4; ++k)
            dst[k] = *reinterpret_cast<const float2*>(
                ybase + (size_t)k * 16 * Tdim * PP + (size_t)t * PP);
    };

    auto step = [&](int t, const float2* y) {
        const float4 wa0 = wr0[t * 4];       // p0,  u quads 2ug / 2ug+1
        const float4 wa1 = wr0[t * 4 + 1];
        const float4 wb0 = wr1[t * 4];       // p0+1
        const float4 wb1 = wr1[t * 4 + 1];
        #pragma unroll
        for (int k = 0; k < 4; ++k) {
            acc[k][0][0] = fmaf(y[k].x, wa0.x, acc[k][0][0]);
            acc[k][0][1] = fmaf(y[k].x, wa0.y, acc[k][0][1]);
            acc[k][0][2] = fmaf(y[k].x, wa0.z, acc[k][0][2]);
            acc[k][0][3] = fmaf(y[k].x, wa0.w, acc[k][0][3]);
            acc[k][0][4] = fmaf(y[k].x, wa1.x, acc[k][0][4]);
            acc[k][0][5] = fmaf(y[k].x, wa1.y, acc[k][0][5]);
            acc[k][0][6] = fmaf(y[k].x, wa1.z, acc[k][0][6]);
            acc[k][0][7] = fmaf(y[k].x, wa1.w, acc[k][0][7]);
            acc[k][1][0] = fmaf(y[k].y, wb0.x, acc[k][1][0]);
            acc[k][1][1] = fmaf(y[k].y, wb0.y, acc[k][1][1]);
            acc[k][1][2] = fmaf(y[k].y, wb0.z, acc[k][1][2]);
            acc[k][1][3] = fmaf(y[k].y, wb0.w, acc[k][1][3]);
            acc[k][1][4] = fmaf(y[k].y, wb1.x, acc[k][1][4]);
            acc[k][1][5] = fmaf(y[k].y, wb1.y, acc[k][1][5]);
            acc[k][1][6] = fmaf(y[k].y, wb1.z, acc[k][1][6]);
            acc[k][1][7] = fmaf(y[k].y, wb1.w, acc[k][1][7]);
        }
    };

    // ---- main loop: depth-2 ping-pong on yt (static indexing), no barriers ------
    float2 yc[4], yn[4];
    ldy(0, yc);
    ldy(1, yn);

    #pragma unroll 1
    for (int t = 0; t < Tdim; t += 2) {
        step(t, yc);
        if (t + 2 < Tdim) ldy(t + 2, yc);
        step(t + 1, yn);
        if (t + 3 < Tdim) ldy(t + 3, yn);
    }

    // ---- epilogue: pixel-shuffle scatter, 16B contiguous per store ---------------
    const int s1   = p_blk / Sdim;
    const int s2_0 = p_blk % Sdim;

    #pragma unroll
    for (int k = 0; k < 4; ++k) {
        const int b = bq + 16 * k;
        float* ob = out + (size_t)b * (512 * 512);
        #pragma unroll
        for (int jp = 0; jp < 2; ++jp) {
            const int c0 = (s2_0 + pg * 2 + jp) * 4;
            #pragma unroll
            for (int half = 0; half < 2; ++half) {
                const int r = s1 * 4 + ug * 2 + half;
                float4 v;
                v.x = acc[k][jp][half * 4 + 0];
                v.y = acc[k][jp][half * 4 + 1];
                v.z = acc[k][jp][half * 4 + 2];
                v.w = acc[k][jp][half * 4 + 3];
                *reinterpret_cast<float4*>(ob + (size_t)r * 512 + c0) = v;
            }
        }
    }
}

extern "C" void kernel_launch(void* const* d_in, const int* in_sizes, int n_in,
                              void* d_out, int out_size, void* d_ws, size_t ws_size,
                              hipStream_t stream)
{
    const float* yt   = (const float*)d_in[0];
    const float* wgt  = (const float*)d_in[1];
    const float* bias = (const float*)d_in[2];
    float* outp       = (float*)d_out;

    dim3 grid(PP / PT);     // 512 blocks
    dim3 block(NTHREADS);
    hipLaunchKernelGGL(upscale_fused, grid, block, 0, stream, yt, wgt, bias, outp);
}